// Round 9
// baseline (50.122 us; speedup 1.0000x reference)
//
#include <hip/hip_runtime.h>
#include <math.h>

// SSIM loss, round 9. r8 showed: instruction cuts landed (busy 40->31us) but
// occupancy fell to ~2.6 blocks/CU and stalls grew. This round targets the
// utilization sweet spot between r7 (6 blk/CU, VALU 71%) and r8 (4 blk, 58%):
//   TH=38, IH=48: LDS 25.3 KB -> 6 blocks/CU (24 waves) w/ launch_bounds(256,6)
//   - halo redundancy 1.263 (vs r8 1.185, r7 1.45): +6% phase-1 VALU
//   - phase-2: 5 rows/thread, 15 reads / 5 rows = 3.0/row (vs 2.43)
//   - phase-1 384 units (1.5/thread): imbalance OK with 6 resident blocks
//   - ssim_final widened to 1024 threads.
// Unchanged: dot2 h-blur f32-acc, packed-f16 v-blur, 4 quantities,
// bijective XCD swizzle, deterministic 2-level reduction.

typedef _Float16 h2 __attribute__((ext_vector_type(2)));

#define TH 38
#define IH 48               // TH + 10
#define ROWA 132            // u32 words per aA row: 32 colpairs * 4 q + 4 pad
#define NPIX (16 * 3 * 512 * 512)
#define NRT 14              // row tiles: 14*38 = 532 >= 512 (tail masked)
#define NBLOCKS (48 * NRT * 8)   // 5376; % 8 == 0 -> bijective XCD swizzle

static __device__ __forceinline__ unsigned h2u(h2 v) {
    union { h2 h; unsigned u; } x; x.h = v; return x.u;
}
static __device__ __forceinline__ h2 u2h(unsigned u) {
    union { unsigned u; h2 h; } x; x.u = u; return x.h;
}
static __device__ __forceinline__ h2 pkrtz(float a, float b) {
    auto r = __builtin_amdgcn_cvt_pkrtz(a, b);
    union { decltype(r) f; h2 h; } x; x.f = r; return x.h;
}
static __device__ __forceinline__ float fdot2f(h2 a, h2 b, float c) {
#if __has_builtin(__builtin_amdgcn_fdot2)
    return __builtin_amdgcn_fdot2(a, b, c, false);
#else
    return c + (float)a[0] * (float)b[0] + (float)a[1] * (float)b[1];
#endif
}

__global__ __launch_bounds__(256, 6) void ssim_main(
    const float* __restrict__ X, const float* __restrict__ Y,
    float* __restrict__ partial)
{
    static const float GWF[11] = {
        0.00102838f, 0.00759876f, 0.03600026f, 0.10936083f, 0.21300567f,
        0.26601190f, 0.21300567f, 0.10936083f, 0.03600026f, 0.00759876f,
        0.00102838f};

    // dot2 weight pairs: pair T (rel cols 2T-8, 2T-7) hits output col j with
    // WP[d-2] = (w[d-3], w[d-2]), d = 2T - j, valid d in [2,13]; OOB w -> 0.
    h2 WP[12];
#pragma unroll
    for (int i = 0; i < 12; ++i) {
        const float wlo = (i - 1 >= 0 && i - 1 < 11) ? GWF[i - 1] : 0.f;
        const float whi = (i < 11) ? GWF[i] : 0.f;
        WP[i] = pkrtz(wlo, whi);
    }
    h2 WV2[11];
#pragma unroll
    for (int k = 0; k < 11; ++k)
        WV2[k] = pkrtz(GWF[k], GWF[k]);

    __shared__ __align__(16) unsigned aA[IH * ROWA];  // 25,344 B
    __shared__ float red[4];

    const int tid = threadIdx.x;
    const int bid = blockIdx.x;

    // bijective XCD swizzle: each XCD gets NBLOCKS/8 consecutive tiles
    const int wg    = (bid & 7) * (NBLOCKS / 8) + (bid >> 3);
    const int plane = wg / (NRT * 8);
    const int tt    = wg - plane * (NRT * 8);
    const int tr    = tt >> 3;          // 0..13
    const int tc    = tt & 7;           // 0..7

    const float* xp = X + (size_t)plane * (512 * 512);
    const float* yp = Y + (size_t)plane * (512 * 512);
    const int row0 = tr * TH - 5;       // global row of aA row 0
    const int colT = tc * 64;           // global col of output col 0

    // ---------------- Phase 1: horizontal blur, 8 cols/unit, 384 units ------
    for (int u = tid; u < IH * 8; u += 256) {
        const int r  = u >> 3;          // 0..47
        const int g8 = u & 7;           // 8-col group
        const int gr = row0 + r;
        const bool rok = ((unsigned)gr < 512u);
        const float* xr = xp + gr * 512;
        const float* yr = yp + gr * 512;
        const int al0 = colT + g8 * 8 - 8;   // aligned window start

        h2 xq[11], yq[11];              // pairs 1..10 used
#pragma unroll
        for (int t = 0; t < 6; ++t) {
            const int ac = al0 + 4 * t;
            const bool ok = rok && (ac >= 0) && (ac <= 508);
            float4 xv = make_float4(0.f, 0.f, 0.f, 0.f), yv = xv;
            if (ok) { xv = *(const float4*)(xr + ac); yv = *(const float4*)(yr + ac); }
            const int p0 = 2 * t, p1 = 2 * t + 1;
            if (p0 >= 1 && p0 <= 10) { xq[p0] = pkrtz(xv.x, xv.y); yq[p0] = pkrtz(yv.x, yv.y); }
            if (p1 >= 1 && p1 <= 10) { xq[p1] = pkrtz(xv.z, xv.w); yq[p1] = pkrtz(yv.z, yv.w); }
        }

        float s0[8], s1[8], s2[8], s3[8];
#pragma unroll
        for (int j = 0; j < 8; ++j) { s0[j]=0.f; s1[j]=0.f; s2[j]=0.f; s3[j]=0.f; }

#pragma unroll
        for (int T = 1; T <= 10; ++T) {
            const h2 xa = xq[T], ya = yq[T];
            const h2 xy = xa * ya;
            const h2 ss = ya * ya + xa * xa;     // pk_mul + pk_fma
#pragma unroll
            for (int j = 0; j < 8; ++j) {
                const int d = 2 * T - j;         // compile-time
                if (d >= 2 && d <= 13) {
                    const h2 W = WP[d - 2];
                    s0[j] = fdot2f(xa, W, s0[j]);
                    s1[j] = fdot2f(ya, W, s1[j]);
                    s2[j] = fdot2f(ss, W, s2[j]);
                    s3[j] = fdot2f(xy, W, s3[j]);
                }
            }
        }

        // store: aA[r][colpair = g8*4 + t2] = {q0,q1,q2,q3} packed
        unsigned* wa = aA + r * ROWA + g8 * 16;
#pragma unroll
        for (int t2 = 0; t2 < 4; ++t2) {
            uint4 W4;
            W4.x = h2u(pkrtz(s0[2*t2], s0[2*t2+1]));
            W4.y = h2u(pkrtz(s1[2*t2], s1[2*t2+1]));
            W4.z = h2u(pkrtz(s2[2*t2], s2[2*t2+1]));
            W4.w = h2u(pkrtz(s3[2*t2], s3[2*t2+1]));
            *(uint4*)(wa + 4 * t2) = W4;
        }
    }
    __syncthreads();

    // ---------------- Phase 2: vertical blur (packed col pairs) -------------
    // thread = (cp in [0,32)) x (g2 in [0,8)); g2 owns rows rb..rb+4
    const int cp = tid & 31;
    const int g2 = tid >> 5;
    const int rb = g2 * 5;              // 0,5,..,35 (rows 38,39 masked)

    h2 m0[5], m1[5], m2[5], m3[5];
#pragma unroll
    for (int j = 0; j < 5; ++j) {
        m0[j] = u2h(0u); m1[j] = u2h(0u); m2[j] = u2h(0u); m3[j] = u2h(0u);
    }

#pragma unroll
    for (int rr = 0; rr < 15; ++rr) {
        const int row = (rb + rr < IH) ? (rb + rr) : (IH - 1);  // junk -> masked j
        const uint4 w4 = *(const uint4*)(aA + row * ROWA + cp * 4);
        const h2 q0 = u2h(w4.x), q1 = u2h(w4.y);
        const h2 q2 = u2h(w4.z), q3 = u2h(w4.w);
#pragma unroll
        for (int j = 0; j < 5; ++j) {
            const int k = rr - j;                  // compile-time
            if (k >= 0 && k < 11) {
                const h2 w = WV2[k];
                m0[j] = w * q0 + m0[j];
                m1[j] = w * q1 + m1[j];
                m2[j] = w * q2 + m2[j];
                m3[j] = w * q3 + m3[j];
            }
        }
    }

    // ---------------- SSIM map + reduction ----------------
    const float C1 = 0.0004f, C2 = 0.0036f;
    float lsum = 0.f;
#pragma unroll
    for (int j = 0; j < 5; ++j) {
        const int o = rb + j;                       // tile-local output row
        const bool valid = (o < TH) && (tr * TH + o < 512);
        float acc = 0.f;
#pragma unroll
        for (int hh = 0; hh < 2; ++hh) {
            const float mux = (float)m0[j][hh];
            const float muy = (float)m1[j][hh];
            const float ess = (float)m2[j][hh];    // blur(x^2+y^2)
            const float exy = (float)m3[j][hh];
            const float mux2 = mux * mux, muy2 = muy * muy, muxy = mux * muy;
            const float svar = fmaxf(ess - mux2 - muy2, 0.f);  // sxx+syy
            const float sxy = exy - muxy;
            const float num = (2.f * muxy + C1) * (2.f * sxy + C2);
            const float den = (mux2 + muy2 + C1) * (svar + C2);
            acc += num * __builtin_amdgcn_rcpf(den);
        }
        lsum += valid ? acc : 0.f;
    }

#pragma unroll
    for (int off = 32; off > 0; off >>= 1)
        lsum += __shfl_down(lsum, off, 64);
    if ((tid & 63) == 0) red[tid >> 6] = lsum;
    __syncthreads();
    if (tid == 0)
        partial[bid] = red[0] + red[1] + red[2] + red[3];
}

__global__ void ssim_final(const float* __restrict__ partial,
                           float* __restrict__ out)
{
    const int tid = threadIdx.x;
    double s = 0.0;
    for (int i = tid; i < NBLOCKS; i += 1024) s += (double)partial[i];
#pragma unroll
    for (int off = 32; off > 0; off >>= 1)
        s += __shfl_down(s, off, 64);
    __shared__ double ws[16];
    if ((tid & 63) == 0) ws[tid >> 6] = s;
    __syncthreads();
    if (tid == 0) {
        double tot = 0.0;
#pragma unroll
        for (int i = 0; i < 16; ++i) tot += ws[i];
        out[0] = (float)(1.0 - tot / (double)NPIX);
    }
}

extern "C" void kernel_launch(void* const* d_in, const int* in_sizes, int n_in,
                              void* d_out, int out_size, void* d_ws, size_t ws_size,
                              hipStream_t stream)
{
    const float* x = (const float*)d_in[0];   // pred
    const float* y = (const float*)d_in[1];   // target
    float* partial = (float*)d_ws;            // NBLOCKS*4 = 21,504 B
    float* out = (float*)d_out;

    ssim_main<<<NBLOCKS, 256, 0, stream>>>(x, y, partial);
    ssim_final<<<1, 1024, 0, stream>>>(partial, out);
}

// Round 10
// 47.245 us; speedup vs baseline: 1.0609x; 1.0609x over previous
//
#include <hip/hip_runtime.h>
#include <math.h>

// SSIM loss, round 10. Empirical LDS cliff: VALU util 83%/71% at <=21.5KB LDS
// (r6/r7) vs 58-60% at >=25.6KB (r8/r9), while taller tiles cut busy-time.
// This round: tall NARROW tile to get both.
//   TW=32, TH=64, IH=74: LDS 74x68x4 = 20,128 B (below cliff)
//   - vertical halo 74/64 = 1.156 (r8: 1.185, r9: 1.263)
//   - 8 row tiles x 64 = 512 exact -> ALL masking deleted (no tail, no clamp)
//   - phase-2 perfectly uniform: 16 cp x 16 groups x 4 rows = 256 threads
//   - phase-1 296 units / 256 threads (1.16, mild)
// Unchanged: dot2 h-blur f32-acc, packed-f16 v-blur, 4 quantities,
// bijective XCD swizzle, deterministic 2-level reduction.

typedef _Float16 h2 __attribute__((ext_vector_type(2)));

#define TH 64
#define IH 74               // TH + 10
#define ROWA 68             // u32 words per aA row: 16 colpairs * 4 q + 4 pad
#define NPIX (16 * 3 * 512 * 512)
#define NBLOCKS (48 * 8 * 16)    // 6144; % 8 == 0 -> bijective XCD swizzle

static __device__ __forceinline__ unsigned h2u(h2 v) {
    union { h2 h; unsigned u; } x; x.h = v; return x.u;
}
static __device__ __forceinline__ h2 u2h(unsigned u) {
    union { unsigned u; h2 h; } x; x.u = u; return x.h;
}
static __device__ __forceinline__ h2 pkrtz(float a, float b) {
    auto r = __builtin_amdgcn_cvt_pkrtz(a, b);
    union { decltype(r) f; h2 h; } x; x.f = r; return x.h;
}
static __device__ __forceinline__ float fdot2f(h2 a, h2 b, float c) {
#if __has_builtin(__builtin_amdgcn_fdot2)
    return __builtin_amdgcn_fdot2(a, b, c, false);
#else
    return c + (float)a[0] * (float)b[0] + (float)a[1] * (float)b[1];
#endif
}

__global__ __launch_bounds__(256, 6) void ssim_main(
    const float* __restrict__ X, const float* __restrict__ Y,
    float* __restrict__ partial)
{
    static const float GWF[11] = {
        0.00102838f, 0.00759876f, 0.03600026f, 0.10936083f, 0.21300567f,
        0.26601190f, 0.21300567f, 0.10936083f, 0.03600026f, 0.00759876f,
        0.00102838f};

    // dot2 weight pairs: pair T (rel cols 2T-8, 2T-7) hits output col j with
    // WP[d-2] = (w[d-3], w[d-2]), d = 2T - j, valid d in [2,13]; OOB w -> 0.
    h2 WP[12];
#pragma unroll
    for (int i = 0; i < 12; ++i) {
        const float wlo = (i - 1 >= 0 && i - 1 < 11) ? GWF[i - 1] : 0.f;
        const float whi = (i < 11) ? GWF[i] : 0.f;
        WP[i] = pkrtz(wlo, whi);
    }
    h2 WV2[11];
#pragma unroll
    for (int k = 0; k < 11; ++k)
        WV2[k] = pkrtz(GWF[k], GWF[k]);

    __shared__ __align__(16) unsigned aA[IH * ROWA];  // 20,128 B
    __shared__ float red[4];

    const int tid = threadIdx.x;
    const int bid = blockIdx.x;

    // bijective XCD swizzle: each XCD gets NBLOCKS/8 consecutive tiles
    const int wg    = (bid & 7) * (NBLOCKS / 8) + (bid >> 3);
    const int plane = wg >> 7;          // 128 tiles per plane
    const int tt    = wg & 127;
    const int tr    = tt >> 4;          // 0..7
    const int tc    = tt & 15;          // 0..15

    const float* xp = X + (size_t)plane * (512 * 512);
    const float* yp = Y + (size_t)plane * (512 * 512);
    const int row0 = tr * TH - 5;       // global row of aA row 0
    const int colT = tc * 32;           // global col of output col 0

    // ---------------- Phase 1: horizontal blur, 8 cols/unit, 296 units ------
    for (int u = tid; u < IH * 4; u += 256) {
        const int r  = u >> 2;          // 0..73
        const int g8 = u & 3;           // 8-col group
        const int gr = row0 + r;
        const bool rok = ((unsigned)gr < 512u);
        const float* xr = xp + gr * 512;
        const float* yr = yp + gr * 512;
        const int al0 = colT + g8 * 8 - 8;   // aligned window start

        h2 xq[11], yq[11];              // pairs 1..10 used
#pragma unroll
        for (int t = 0; t < 6; ++t) {
            const int ac = al0 + 4 * t;
            const bool ok = rok && (ac >= 0) && (ac <= 508);
            float4 xv = make_float4(0.f, 0.f, 0.f, 0.f), yv = xv;
            if (ok) { xv = *(const float4*)(xr + ac); yv = *(const float4*)(yr + ac); }
            const int p0 = 2 * t, p1 = 2 * t + 1;
            if (p0 >= 1 && p0 <= 10) { xq[p0] = pkrtz(xv.x, xv.y); yq[p0] = pkrtz(yv.x, yv.y); }
            if (p1 >= 1 && p1 <= 10) { xq[p1] = pkrtz(xv.z, xv.w); yq[p1] = pkrtz(yv.z, yv.w); }
        }

        float s0[8], s1[8], s2[8], s3[8];
#pragma unroll
        for (int j = 0; j < 8; ++j) { s0[j]=0.f; s1[j]=0.f; s2[j]=0.f; s3[j]=0.f; }

#pragma unroll
        for (int T = 1; T <= 10; ++T) {
            const h2 xa = xq[T], ya = yq[T];
            const h2 xy = xa * ya;
            const h2 ss = ya * ya + xa * xa;     // pk_mul + pk_fma
#pragma unroll
            for (int j = 0; j < 8; ++j) {
                const int d = 2 * T - j;         // compile-time
                if (d >= 2 && d <= 13) {
                    const h2 W = WP[d - 2];
                    s0[j] = fdot2f(xa, W, s0[j]);
                    s1[j] = fdot2f(ya, W, s1[j]);
                    s2[j] = fdot2f(ss, W, s2[j]);
                    s3[j] = fdot2f(xy, W, s3[j]);
                }
            }
        }

        // store: aA[r][colpair = g8*4 + t2] = {q0,q1,q2,q3} packed
        unsigned* wa = aA + r * ROWA + g8 * 16;
#pragma unroll
        for (int t2 = 0; t2 < 4; ++t2) {
            uint4 W4;
            W4.x = h2u(pkrtz(s0[2*t2], s0[2*t2+1]));
            W4.y = h2u(pkrtz(s1[2*t2], s1[2*t2+1]));
            W4.z = h2u(pkrtz(s2[2*t2], s2[2*t2+1]));
            W4.w = h2u(pkrtz(s3[2*t2], s3[2*t2+1]));
            *(uint4*)(wa + 4 * t2) = W4;
        }
    }
    __syncthreads();

    // ---------------- Phase 2: vertical blur (packed col pairs) -------------
    // thread = (cp in [0,16)) x (g in [0,16)); g owns rows g*4 .. g*4+3.
    const int cp = tid & 15;
    const int g  = tid >> 4;
    const int rb = g * 4;               // 0,4,..,60; taps reach rb+13 <= 73 ✓

    h2 m0[4], m1[4], m2[4], m3[4];
#pragma unroll
    for (int j = 0; j < 4; ++j) {
        m0[j] = u2h(0u); m1[j] = u2h(0u); m2[j] = u2h(0u); m3[j] = u2h(0u);
    }

#pragma unroll
    for (int rr = 0; rr < 14; ++rr) {
        const int row = rb + rr;
        const uint4 w4 = *(const uint4*)(aA + row * ROWA + cp * 4);
        const h2 q0 = u2h(w4.x), q1 = u2h(w4.y);
        const h2 q2 = u2h(w4.z), q3 = u2h(w4.w);
#pragma unroll
        for (int j = 0; j < 4; ++j) {
            const int k = rr - j;                  // compile-time
            if (k >= 0 && k < 11) {
                const h2 w = WV2[k];
                m0[j] = w * q0 + m0[j];
                m1[j] = w * q1 + m1[j];
                m2[j] = w * q2 + m2[j];
                m3[j] = w * q3 + m3[j];
            }
        }
    }

    // ---------------- SSIM map + reduction (no masking: 8x64=512 exact) -----
    const float C1 = 0.0004f, C2 = 0.0036f;
    float lsum = 0.f;
#pragma unroll
    for (int j = 0; j < 4; ++j) {
#pragma unroll
        for (int hh = 0; hh < 2; ++hh) {
            const float mux = (float)m0[j][hh];
            const float muy = (float)m1[j][hh];
            const float ess = (float)m2[j][hh];    // blur(x^2+y^2)
            const float exy = (float)m3[j][hh];
            const float mux2 = mux * mux, muy2 = muy * muy, muxy = mux * muy;
            const float svar = fmaxf(ess - mux2 - muy2, 0.f);  // sxx+syy
            const float sxy = exy - muxy;
            const float num = (2.f * muxy + C1) * (2.f * sxy + C2);
            const float den = (mux2 + muy2 + C1) * (svar + C2);
            lsum += num * __builtin_amdgcn_rcpf(den);
        }
    }

#pragma unroll
    for (int off = 32; off > 0; off >>= 1)
        lsum += __shfl_down(lsum, off, 64);
    if ((tid & 63) == 0) red[tid >> 6] = lsum;
    __syncthreads();
    if (tid == 0)
        partial[bid] = red[0] + red[1] + red[2] + red[3];
}

__global__ void ssim_final(const float* __restrict__ partial,
                           float* __restrict__ out)
{
    const int tid = threadIdx.x;
    double s = 0.0;
    for (int i = tid; i < NBLOCKS; i += 1024) s += (double)partial[i];
#pragma unroll
    for (int off = 32; off > 0; off >>= 1)
        s += __shfl_down(s, off, 64);
    __shared__ double ws[16];
    if ((tid & 63) == 0) ws[tid >> 6] = s;
    __syncthreads();
    if (tid == 0) {
        double tot = 0.0;
#pragma unroll
        for (int i = 0; i < 16; ++i) tot += ws[i];
        out[0] = (float)(1.0 - tot / (double)NPIX);
    }
}

extern "C" void kernel_launch(void* const* d_in, const int* in_sizes, int n_in,
                              void* d_out, int out_size, void* d_ws, size_t ws_size,
                              hipStream_t stream)
{
    const float* x = (const float*)d_in[0];   // pred
    const float* y = (const float*)d_in[1];   // target
    float* partial = (float*)d_ws;            // NBLOCKS*4 = 24,576 B
    float* out = (float*)d_out;

    ssim_main<<<NBLOCKS, 256, 0, stream>>>(x, y, partial);
    ssim_final<<<1, 1024, 0, stream>>>(partial, out);
}

// Round 11
// 43.919 us; speedup vs baseline: 1.1412x; 1.0757x over previous
//
#include <hip/hip_runtime.h>
#include <math.h>

// SSIM loss, round 11: blurs on matrix cores, designed around r4's failures.
//  - No raw staging: lane loads its A-fragment's 8 px (4 float4), packs once,
//    builds all 4 quantity frags {x, y, x^2+y^2, xy} from one load.
//  - K=32 band: 16 out cols need 26 in cols -> 1 MFMA per (mt,nt,q).
//  - S[n][k] f16 pitch 56: h-blur C writes f16x4 contiguous, v-blur B-frag
//    reads f16x8 contiguous; each wave reads only its own n-range.
//  - Tile TW=64, TH=32 (16x8 tiles of 512^2 exact -> no output masking),
//    IH=48 staged h-rows. LDS 28.7 KB -> 5 blocks/CU.
// Verified layouts (r4 passed): A/B frag lane&15 = m/n, k = 8*(lane>>4)+j;
// C/D: col = lane&15, row = 4*(lane>>4)+reg.
// Per-thread VALU ~310 (was ~690): blur FMAs moved to matrix pipe.

typedef _Float16 f16x8 __attribute__((ext_vector_type(8)));
typedef _Float16 f16x4 __attribute__((ext_vector_type(4)));
typedef float f32x4 __attribute__((ext_vector_type(4)));
typedef _Float16 h2 __attribute__((ext_vector_type(2)));

#define PS 56                    // f16 pitch of S rows (48 data + 8 pad)
#define PLANE (64 * PS)          // f16 per quantity plane
#define NPIX (16 * 3 * 512 * 512)
#define NBLOCKS (48 * 16 * 8)    // 6144; % 8 == 0 -> bijective XCD swizzle

union U8 { f16x8 v; h2 p[4]; };
union U4 { f16x4 v; h2 p[2]; };

static __device__ __forceinline__ h2 pkrtz(float a, float b) {
    auto r = __builtin_amdgcn_cvt_pkrtz(a, b);
    union { decltype(r) f; h2 h; } x; x.f = r; return x.h;
}

__global__ __launch_bounds__(256, 5) void ssim_main(
    const float* __restrict__ X, const float* __restrict__ Y,
    float* __restrict__ partial)
{
    static const float GWF[11] = {
        0.00102838f, 0.00759876f, 0.03600026f, 0.10936083f, 0.21300567f,
        0.26601190f, 0.21300567f, 0.10936083f, 0.03600026f, 0.00759876f,
        0.00102838f};

    __shared__ _Float16 S[4 * PLANE];    // 28,672 B
    __shared__ _Float16 wtab[16];        // wtab[0]=0, [1..11]=w[0..10], rest 0
    __shared__ float red[4];

    const int tid = threadIdx.x;
    const int bid = blockIdx.x;

    if (tid < 16)
        wtab[tid] = (tid >= 1 && tid <= 11) ? (_Float16)GWF[tid - 1]
                                            : (_Float16)0.0f;

    // bijective XCD swizzle
    const int wg    = (bid & 7) * (NBLOCKS / 8) + (bid >> 3);
    const int plane = wg >> 7;           // 128 tiles per plane
    const int tt    = wg & 127;
    const int tr    = tt >> 3;           // 0..15 (row tiles, 32 rows each)
    const int tc    = tt & 7;            // 0..7  (col tiles, 64 cols each)

    const float* xp = X + (size_t)plane * (512 * 512);
    const float* yp = Y + (size_t)plane * (512 * 512);
    const int row0 = tr * 32 - 5;        // global row of S k-row 0
    const int colT = tc * 64;            // global col of output col 0

    const int w   = tid >> 6;            // wave id = n-tile
    const int lane = tid & 63;
    const int l15 = lane & 15;
    const int kg  = lane >> 4;

    __syncthreads();                     // wtab ready

    // ---- band fragments (8 ds_read_u16 each, one-time) ----
    // h-blur B: Bh[k][n] = w[k-n-3] -> wtab[k-n-2]; v-blur A: Wv[m][k]=w[k-m]
    f16x8 BH, WV;
#pragma unroll
    for (int j = 0; j < 8; ++j) {
        const int kk = kg * 8 + j;
        int ib = kk - l15 - 2; ib = ib < 0 ? 0 : (ib > 15 ? 15 : ib);
        int iv = kk - l15 + 1; iv = iv < 0 ? 0 : (iv > 15 ? 15 : iv);
        BH[j] = wtab[ib];
        WV[j] = wtab[iv];
    }

    const f32x4 zero4 = {0.f, 0.f, 0.f, 0.f};

    // ---- Phase A+B: load + products + h-blur MFMA + S write ----
    // wave w = n-tile (out cols 16w..16w+15); A k-window global cols
    // colT+16w-8 .. +24. Lane loads rows mt*16+l15, cols colA..colA+7.
    const int colA = colT + 16 * w - 8 + kg * 8;   // multiple of 8
    const bool ok0 = (colA >= 0) && (colA <= 508);
    const bool ok1 = (colA + 4 >= 0) && (colA + 4 <= 508);

#pragma unroll
    for (int mt = 0; mt < 3; ++mt) {
        const int r  = mt * 16 + l15;    // S k-row
        const int gr = row0 + r;
        const bool rok = ((unsigned)gr < 512u);
        const float* xr = xp + gr * 512;
        const float* yr = yp + gr * 512;
        float4 xv0 = make_float4(0.f,0.f,0.f,0.f), xv1 = xv0, yv0 = xv0, yv1 = xv0;
        if (rok && ok0) { xv0 = *(const float4*)(xr + colA);     yv0 = *(const float4*)(yr + colA); }
        if (rok && ok1) { xv1 = *(const float4*)(xr + colA + 4); yv1 = *(const float4*)(yr + colA + 4); }

        U8 fx, fy;
        fx.p[0] = pkrtz(xv0.x, xv0.y); fx.p[1] = pkrtz(xv0.z, xv0.w);
        fx.p[2] = pkrtz(xv1.x, xv1.y); fx.p[3] = pkrtz(xv1.z, xv1.w);
        fy.p[0] = pkrtz(yv0.x, yv0.y); fy.p[1] = pkrtz(yv0.z, yv0.w);
        fy.p[2] = pkrtz(yv1.x, yv1.y); fy.p[3] = pkrtz(yv1.z, yv1.w);

        const f16x8 fxy = fx.v * fy.v;
        const f16x8 fss = fx.v * fx.v + fy.v * fy.v;

        const f32x4 c0 = __builtin_amdgcn_mfma_f32_16x16x32_f16(fx.v, BH, zero4, 0, 0, 0);
        const f32x4 c1 = __builtin_amdgcn_mfma_f32_16x16x32_f16(fy.v, BH, zero4, 0, 0, 0);
        const f32x4 c2 = __builtin_amdgcn_mfma_f32_16x16x32_f16(fss,  BH, zero4, 0, 0, 0);
        const f32x4 c3 = __builtin_amdgcn_mfma_f32_16x16x32_f16(fxy,  BH, zero4, 0, 0, 0);

        // C layout: col = l15 (= n), rows = 4*kg + (0..3) -> S[n][mt*16+4kg..+3]
        const int srow = 16 * w + l15;
        const int koff = mt * 16 + 4 * kg;
        _Float16* sp = S + srow * PS + koff;
        U4 t0, t1, t2, t3;
        t0.p[0] = pkrtz(c0[0], c0[1]); t0.p[1] = pkrtz(c0[2], c0[3]);
        t1.p[0] = pkrtz(c1[0], c1[1]); t1.p[1] = pkrtz(c1[2], c1[3]);
        t2.p[0] = pkrtz(c2[0], c2[1]); t2.p[1] = pkrtz(c2[2], c2[3]);
        t3.p[0] = pkrtz(c3[0], c3[1]); t3.p[1] = pkrtz(c3[2], c3[3]);
        *(f16x4*)(sp + 0 * PLANE) = t0.v;
        *(f16x4*)(sp + 1 * PLANE) = t1.v;
        *(f16x4*)(sp + 2 * PLANE) = t2.v;
        *(f16x4*)(sp + 3 * PLANE) = t3.v;
    }
    __syncthreads();

    // ---- Phase C: v-blur MFMA + SSIM epilogue ----
    // B-frag: lane (l15,kg) reads S[n=16w+l15][16mtv + 8kg .. +7] (f16x8).
    const float C1 = 0.0004f, C2 = 0.0036f;
    float lsum = 0.f;
#pragma unroll
    for (int mtv = 0; mtv < 2; ++mtv) {
        const _Float16* sp = S + (16 * w + l15) * PS + 16 * mtv + kg * 8;
        const f16x8 b0 = *(const f16x8*)(sp + 0 * PLANE);
        const f16x8 b1 = *(const f16x8*)(sp + 1 * PLANE);
        const f16x8 b2 = *(const f16x8*)(sp + 2 * PLANE);
        const f16x8 b3 = *(const f16x8*)(sp + 3 * PLANE);
        const f32x4 v0 = __builtin_amdgcn_mfma_f32_16x16x32_f16(WV, b0, zero4, 0, 0, 0);
        const f32x4 v1 = __builtin_amdgcn_mfma_f32_16x16x32_f16(WV, b1, zero4, 0, 0, 0);
        const f32x4 v2 = __builtin_amdgcn_mfma_f32_16x16x32_f16(WV, b2, zero4, 0, 0, 0);
        const f32x4 v3 = __builtin_amdgcn_mfma_f32_16x16x32_f16(WV, b3, zero4, 0, 0, 0);
#pragma unroll
        for (int r2 = 0; r2 < 4; ++r2) {
            const float mux = v0[r2], muy = v1[r2];
            const float ess = v2[r2], exy = v3[r2];
            const float mux2 = mux * mux, muy2 = muy * muy, muxy = mux * muy;
            const float svar = fmaxf(ess - mux2 - muy2, 0.f);  // sxx+syy
            const float sxy = exy - muxy;
            const float num = (2.f * muxy + C1) * (2.f * sxy + C2);
            const float den = (mux2 + muy2 + C1) * (svar + C2);
            lsum += num * __builtin_amdgcn_rcpf(den);
        }
    }

#pragma unroll
    for (int off = 32; off > 0; off >>= 1)
        lsum += __shfl_down(lsum, off, 64);
    if (lane == 0) red[w] = lsum;
    __syncthreads();
    if (tid == 0)
        partial[bid] = red[0] + red[1] + red[2] + red[3];
}

__global__ void ssim_final(const float* __restrict__ partial,
                           float* __restrict__ out)
{
    const int tid = threadIdx.x;
    double s = 0.0;
    for (int i = tid; i < NBLOCKS; i += 1024) s += (double)partial[i];
#pragma unroll
    for (int off = 32; off > 0; off >>= 1)
        s += __shfl_down(s, off, 64);
    __shared__ double ws[16];
    if ((tid & 63) == 0) ws[tid >> 6] = s;
    __syncthreads();
    if (tid == 0) {
        double tot = 0.0;
#pragma unroll
        for (int i = 0; i < 16; ++i) tot += ws[i];
        out[0] = (float)(1.0 - tot / (double)NPIX);
    }
}

extern "C" void kernel_launch(void* const* d_in, const int* in_sizes, int n_in,
                              void* d_out, int out_size, void* d_ws, size_t ws_size,
                              hipStream_t stream)
{
    const float* x = (const float*)d_in[0];   // pred
    const float* y = (const float*)d_in[1];   // target
    float* partial = (float*)d_ws;            // NBLOCKS*4 = 24,576 B
    float* out = (float*)d_out;

    ssim_main<<<NBLOCKS, 256, 0, stream>>>(x, y, partial);
    ssim_final<<<1, 1024, 0, stream>>>(partial, out);
}

// Round 12
// 41.096 us; speedup vs baseline: 1.2196x; 1.0687x over previous
//
#include <hip/hip_runtime.h>
#include <math.h>

// SSIM loss, round 12. r11 diagnosis: both pipes idle (VALU 29%, MFMA 6%),
// floor = TA line throughput: phase-A fragment loads are row-strided, a wave
// load touches ~48 cache lines (ideal 16) -> ~23us/CU of line time.
// Fix: stage raw tile in LDS once, COALESCED (lane->consecutive cols,
// f32->f16 convert during staging); fragments then come from ds_read_b128.
//   raw[48][88] f16 x2: pitch 11x16B -> fragment reads 2-way banks (free).
//   Unique loads only: 30.7 KB/block, 16 lines per wave-load.
// Unchanged from r11 (verified): K=32 band MFMA h-blur, S[n][k] f16 pitch 56
// transpose, v-blur MFMA, register epilogue, XCD swizzle, 2-level reduce.
// LDS 45.6 KB -> 3 blocks/CU (occupancy proven non-critical in r8-r10).

typedef _Float16 f16x8 __attribute__((ext_vector_type(8)));
typedef _Float16 f16x4 __attribute__((ext_vector_type(4)));
typedef float f32x4 __attribute__((ext_vector_type(4)));
typedef _Float16 h2 __attribute__((ext_vector_type(2)));

#define RAWP 88                  // f16 pitch of raw rows (80 data + 8 pad)
#define PS 56                    // f16 pitch of S rows (48 data + 8 pad)
#define PLANE (64 * PS)          // f16 per S quantity plane
#define NPIX (16 * 3 * 512 * 512)
#define NBLOCKS (48 * 16 * 8)    // 6144; % 8 == 0 -> bijective XCD swizzle

union U8 { f16x8 v; h2 p[4]; };
union U4 { f16x4 v; h2 p[2]; };

static __device__ __forceinline__ h2 pkrtz(float a, float b) {
    auto r = __builtin_amdgcn_cvt_pkrtz(a, b);
    union { decltype(r) f; h2 h; } x; x.f = r; return x.h;
}

__global__ __launch_bounds__(256, 3) void ssim_main(
    const float* __restrict__ X, const float* __restrict__ Y,
    float* __restrict__ partial)
{
    static const float GWF[11] = {
        0.00102838f, 0.00759876f, 0.03600026f, 0.10936083f, 0.21300567f,
        0.26601190f, 0.21300567f, 0.10936083f, 0.03600026f, 0.00759876f,
        0.00102838f};

    __shared__ _Float16 rawx[48 * RAWP];   // 8,448 B
    __shared__ _Float16 rawy[48 * RAWP];   // 8,448 B
    __shared__ _Float16 S[4 * PLANE];      // 28,672 B
    __shared__ _Float16 wtab[16];
    __shared__ float red[4];

    const int tid = threadIdx.x;
    const int bid = blockIdx.x;

    if (tid < 16)
        wtab[tid] = (tid >= 1 && tid <= 11) ? (_Float16)GWF[tid - 1]
                                            : (_Float16)0.0f;

    // bijective XCD swizzle
    const int wg    = (bid & 7) * (NBLOCKS / 8) + (bid >> 3);
    const int plane = wg >> 7;           // 128 tiles per plane
    const int tt    = wg & 127;
    const int tr    = tt >> 3;           // 0..15 (row tiles, 32 rows)
    const int tc    = tt & 7;            // 0..7  (col tiles, 64 cols)

    const float* xp = X + (size_t)plane * (512 * 512);
    const float* yp = Y + (size_t)plane * (512 * 512);
    const int row0 = tr * 32 - 5;        // global row of raw row 0
    const int colT = tc * 64;            // global col of output col 0
    const int colB = colT - 8;           // global col of raw col 0

    // ---- coalesced staging: 48 rows x 20 float4-quads, f32 -> f16 ----
    for (int u = tid; u < 960; u += 256) {
        const int r  = u / 20;
        const int c4 = u - r * 20;
        const int gr = row0 + r;
        const int gc = colB + 4 * c4;
        const bool ok = ((unsigned)gr < 512u) && ((unsigned)gc <= 508u);
        float4 xv = make_float4(0.f, 0.f, 0.f, 0.f), yv = xv;
        if (ok) {
            xv = *(const float4*)(xp + gr * 512 + gc);
            yv = *(const float4*)(yp + gr * 512 + gc);
        }
        U4 tx, ty;
        tx.p[0] = pkrtz(xv.x, xv.y); tx.p[1] = pkrtz(xv.z, xv.w);
        ty.p[0] = pkrtz(yv.x, yv.y); ty.p[1] = pkrtz(yv.z, yv.w);
        *(f16x4*)(rawx + r * RAWP + 4 * c4) = tx.v;
        *(f16x4*)(rawy + r * RAWP + 4 * c4) = ty.v;
    }
    __syncthreads();

    const int w    = tid >> 6;           // wave id = n-tile (out cols 16w..)
    const int lane = tid & 63;
    const int l15  = lane & 15;
    const int kg   = lane >> 4;

    // ---- band fragments from wtab ----
    // h-blur B: Bh[k][n] = w[k-n-3] -> wtab[k-n-2]; v-blur A: Wv[m][k]=w[k-m]
    f16x8 BH, WV;
#pragma unroll
    for (int j = 0; j < 8; ++j) {
        const int kk = kg * 8 + j;
        int ib = kk - l15 - 2; ib = ib < 0 ? 0 : (ib > 15 ? 15 : ib);
        int iv = kk - l15 + 1; iv = iv < 0 ? 0 : (iv > 15 ? 15 : iv);
        BH[j] = wtab[ib];
        WV[j] = wtab[iv];
    }

    const f32x4 zero4 = {0.f, 0.f, 0.f, 0.f};

    // ---- Phase A: fragments from LDS, products, h-blur MFMA, S write ----
    // A k=0 is global col colT+16w-8 = raw col 16w; lane reads 8 f16 at
    // raw[mt*16+l15][16w + 8kg] (16B aligned; row stride 11x16B -> 2-way).
    const int rawc = 16 * w + 8 * kg;
#pragma unroll
    for (int mt = 0; mt < 3; ++mt) {
        const int r = mt * 16 + l15;
        const f16x8 fx = *(const f16x8*)(rawx + r * RAWP + rawc);
        const f16x8 fy = *(const f16x8*)(rawy + r * RAWP + rawc);
        const f16x8 fxy = fx * fy;
        const f16x8 fss = fx * fx + fy * fy;

        const f32x4 c0 = __builtin_amdgcn_mfma_f32_16x16x32_f16(fx,  BH, zero4, 0, 0, 0);
        const f32x4 c1 = __builtin_amdgcn_mfma_f32_16x16x32_f16(fy,  BH, zero4, 0, 0, 0);
        const f32x4 c2 = __builtin_amdgcn_mfma_f32_16x16x32_f16(fss, BH, zero4, 0, 0, 0);
        const f32x4 c3 = __builtin_amdgcn_mfma_f32_16x16x32_f16(fxy, BH, zero4, 0, 0, 0);

        // C layout: col=l15 (=n), rows=4kg..4kg+3 -> S[16w+l15][mt*16+4kg]
        _Float16* sp = S + (16 * w + l15) * PS + mt * 16 + 4 * kg;
        U4 t0, t1, t2, t3;
        t0.p[0] = pkrtz(c0[0], c0[1]); t0.p[1] = pkrtz(c0[2], c0[3]);
        t1.p[0] = pkrtz(c1[0], c1[1]); t1.p[1] = pkrtz(c1[2], c1[3]);
        t2.p[0] = pkrtz(c2[0], c2[1]); t2.p[1] = pkrtz(c2[2], c2[3]);
        t3.p[0] = pkrtz(c3[0], c3[1]); t3.p[1] = pkrtz(c3[2], c3[3]);
        *(f16x4*)(sp + 0 * PLANE) = t0.v;
        *(f16x4*)(sp + 1 * PLANE) = t1.v;
        *(f16x4*)(sp + 2 * PLANE) = t2.v;
        *(f16x4*)(sp + 3 * PLANE) = t3.v;
    }
    __syncthreads();

    // ---- Phase C: v-blur MFMA + SSIM epilogue ----
    const float C1 = 0.0004f, C2 = 0.0036f;
    float lsum = 0.f;
#pragma unroll
    for (int mtv = 0; mtv < 2; ++mtv) {
        const _Float16* sp = S + (16 * w + l15) * PS + 16 * mtv + kg * 8;
        const f16x8 b0 = *(const f16x8*)(sp + 0 * PLANE);
        const f16x8 b1 = *(const f16x8*)(sp + 1 * PLANE);
        const f16x8 b2 = *(const f16x8*)(sp + 2 * PLANE);
        const f16x8 b3 = *(const f16x8*)(sp + 3 * PLANE);
        const f32x4 v0 = __builtin_amdgcn_mfma_f32_16x16x32_f16(WV, b0, zero4, 0, 0, 0);
        const f32x4 v1 = __builtin_amdgcn_mfma_f32_16x16x32_f16(WV, b1, zero4, 0, 0, 0);
        const f32x4 v2 = __builtin_amdgcn_mfma_f32_16x16x32_f16(WV, b2, zero4, 0, 0, 0);
        const f32x4 v3 = __builtin_amdgcn_mfma_f32_16x16x32_f16(WV, b3, zero4, 0, 0, 0);
#pragma unroll
        for (int r2 = 0; r2 < 4; ++r2) {
            const float mux = v0[r2], muy = v1[r2];
            const float ess = v2[r2], exy = v3[r2];
            const float mux2 = mux * mux, muy2 = muy * muy, muxy = mux * muy;
            const float svar = fmaxf(ess - mux2 - muy2, 0.f);  // sxx+syy
            const float sxy = exy - muxy;
            const float num = (2.f * muxy + C1) * (2.f * sxy + C2);
            const float den = (mux2 + muy2 + C1) * (svar + C2);
            lsum += num * __builtin_amdgcn_rcpf(den);
        }
    }

#pragma unroll
    for (int off = 32; off > 0; off >>= 1)
        lsum += __shfl_down(lsum, off, 64);
    if (lane == 0) red[w] = lsum;
    __syncthreads();
    if (tid == 0)
        partial[bid] = red[0] + red[1] + red[2] + red[3];
}

__global__ void ssim_final(const float* __restrict__ partial,
                           float* __restrict__ out)
{
    const int tid = threadIdx.x;
    double s = 0.0;
    for (int i = tid; i < NBLOCKS; i += 1024) s += (double)partial[i];
#pragma unroll
    for (int off = 32; off > 0; off >>= 1)
        s += __shfl_down(s, off, 64);
    __shared__ double ws[16];
    if ((tid & 63) == 0) ws[tid >> 6] = s;
    __syncthreads();
    if (tid == 0) {
        double tot = 0.0;
#pragma unroll
        for (int i = 0; i < 16; ++i) tot += ws[i];
        out[0] = (float)(1.0 - tot / (double)NPIX);
    }
}

extern "C" void kernel_launch(void* const* d_in, const int* in_sizes, int n_in,
                              void* d_out, int out_size, void* d_ws, size_t ws_size,
                              hipStream_t stream)
{
    const float* x = (const float*)d_in[0];   // pred
    const float* y = (const float*)d_in[1];   // target
    float* partial = (float*)d_ws;            // NBLOCKS*4 = 24,576 B
    float* out = (float*)d_out;

    ssim_main<<<NBLOCKS, 256, 0, stream>>>(x, y, partial);
    ssim_final<<<1, 1024, 0, stream>>>(partial, out);
}